// Round 1
// baseline (326.403 us; speedup 1.0000x reference)
//
#include <hip/hip_runtime.h>
#include <hip/hip_bf16.h>

#define N_ROWS 65536
#define DIM    2048
#define NEXP   8
#define TOPK   2
#define RPW    4              // rows per wave per iteration
#define CHUNKS (DIM / (64 * 4))   // 8 float4-chunks per row per lane

__global__ __launch_bounds__(512, 4) void moe_router_kernel(
    const float* __restrict__ x,
    const float* __restrict__ W,
    const float* __restrict__ b,
    float* __restrict__ out_vals,   // [N, 2] f32
    float* __restrict__ out_idx,    // [N, 2] written as f32
    float* __restrict__ out_x)      // [N, D] f32 (pass-through copy)
{
    __shared__ float sW[NEXP * DIM];   // 64 KiB

    // Cooperative stage of W into LDS (float4, coalesced).
    const float4* W4 = (const float4*)W;
    float4* sW4 = (float4*)sW;
    for (int i = threadIdx.x; i < NEXP * DIM / 4; i += blockDim.x)
        sW4[i] = W4[i];
    __syncthreads();

    float bias[NEXP];
#pragma unroll
    for (int e = 0; e < NEXP; ++e) bias[e] = b[e];

    const int lane   = threadIdx.x & 63;
    const int wave   = (int)((blockIdx.x * blockDim.x + threadIdx.x) >> 6);
    const int nwaves = (int)((gridDim.x * blockDim.x) >> 6);

    const float4* x4 = (const float4*)x;
    float4* ox4 = (float4*)out_x;
    const int row_f4 = DIM / 4;   // float4s per row

    for (int g = wave; g < N_ROWS / RPW; g += nwaves) {
        const int row0 = g * RPW;

        float acc[RPW][NEXP];
#pragma unroll
        for (int r = 0; r < RPW; ++r)
#pragma unroll
            for (int e = 0; e < NEXP; ++e) acc[r][e] = 0.0f;

#pragma unroll
        for (int c = 0; c < CHUNKS; ++c) {
            const int d4 = c * 64 + lane;           // float4 index within row
            float4 xv[RPW];
#pragma unroll
            for (int r = 0; r < RPW; ++r) {
                const size_t off = (size_t)(row0 + r) * row_f4 + d4;
                xv[r] = x4[off];
                ox4[off] = xv[r];                   // fused pass-through copy
            }
#pragma unroll
            for (int e = 0; e < NEXP; ++e) {
                const float4 wv = sW4[e * row_f4 + d4];
#pragma unroll
                for (int r = 0; r < RPW; ++r) {
                    acc[r][e] += xv[r].x * wv.x;
                    acc[r][e] += xv[r].y * wv.y;
                    acc[r][e] += xv[r].z * wv.z;
                    acc[r][e] += xv[r].w * wv.w;
                }
            }
        }

        // Wave-wide butterfly reduce: every lane ends with the full dot product.
#pragma unroll
        for (int r = 0; r < RPW; ++r) {
#pragma unroll
            for (int e = 0; e < NEXP; ++e) {
                float v = acc[r][e];
                v += __shfl_xor(v, 32, 64);
                v += __shfl_xor(v, 16, 64);
                v += __shfl_xor(v, 8, 64);
                v += __shfl_xor(v, 4, 64);
                v += __shfl_xor(v, 2, 64);
                v += __shfl_xor(v, 1, 64);
                acc[r][e] = v + bias[e];
            }
        }

        // Lanes 0..RPW-1 finish one row each: softmax over 8, top-2.
        if (lane < RPW) {
            const int r = lane;
            float lg[NEXP];
#pragma unroll
            for (int e = 0; e < NEXP; ++e) lg[e] = acc[r][e];

            float mx = lg[0];
#pragma unroll
            for (int e = 1; e < NEXP; ++e) mx = fmaxf(mx, lg[e]);

            float p[NEXP];
            float sum = 0.0f;
#pragma unroll
            for (int e = 0; e < NEXP; ++e) { p[e] = __expf(lg[e] - mx); sum += p[e]; }
            const float inv = 1.0f / sum;

            // top-1: strict > keeps the lowest index on ties (jax.lax.top_k order)
            int i1 = 0;
#pragma unroll
            for (int e = 1; e < NEXP; ++e) if (lg[e] > lg[i1]) i1 = e;
            // top-2: lowest-index-first among the rest
            int i2 = (i1 == 0) ? 1 : 0;
#pragma unroll
            for (int e = 0; e < NEXP; ++e)
                if (e != i1 && e != i2 && lg[e] > lg[i2]) i2 = e;

            const int row = row0 + r;
            out_vals[row * 2 + 0] = p[i1] * inv;
            out_vals[row * 2 + 1] = p[i2] * inv;
            out_idx[row * 2 + 0]  = (float)i1;
            out_idx[row * 2 + 1]  = (float)i2;
        }
    }
}

extern "C" void kernel_launch(void* const* d_in, const int* in_sizes, int n_in,
                              void* d_out, int out_size, void* d_ws, size_t ws_size,
                              hipStream_t stream) {
    const float* x = (const float*)d_in[0];
    const float* W = (const float*)d_in[1];
    const float* b = (const float*)d_in[2];

    float* out = (float*)d_out;
    float* out_vals = out;                       // N*2
    float* out_idx  = out + (size_t)N_ROWS * 2;  // N*2
    float* out_x    = out + (size_t)N_ROWS * 4;  // N*D

    moe_router_kernel<<<1024, 512, 0, stream>>>(x, W, b, out_vals, out_idx, out_x);
}